// Round 3
// baseline (688.519 us; speedup 1.0000x reference)
//
#include <hip/hip_runtime.h>
#include <stdint.h>
#include <math.h>

// ---------------------------------------------------------------------------
// MultiScaleResidualQuantizer3D  (B=128, C=32, HW=16, N_E=4096, 10 scales)
// Round 16 == Round 15 resubmit (infra failure, no kernel verdict).
// Round 15: LDS-free k_quant.
//   - SEG=32 => each block sweeps only 128 codes = 8 B-tiles = 64 VGPRs.
//     Keep code fragments IN REGISTERS (direct global loads, L1-hot across
//     the 4 waves) instead of LDS staging. Deletes: staging loop, both
//     __syncthreads, all ds_read/ds_write (and their bank conflicts).
//     Waves run fully independent -> no collective barrier-drain stall.
//   - scores bit-identical to round 14 (same data, same MFMA order).
//   - k_down: float4-vectorized pooling for PN in {1,2,4} (aligned windows),
//     scalar accumulation order preserved exactly.
// Carried from round 14 (measured 589 us):
//   - MFMA swapped (A=codes, B=tokens), packed i32 keys + v_max3_i32,
//     4-lane shfl epilogue, bestp = u32[seg][tok], upconv 32-way merge.
//   - PHI_IDX = [0,0,0,1,1,2,2,2,3,3] (exact np.linspace tie resolution)
// ---------------------------------------------------------------------------

#define DEVI __device__ __forceinline__

static constexpr int NE = 4096;

typedef _Float16 half8 __attribute__((ext_vector_type(8)));
typedef float floatx4 __attribute__((ext_vector_type(4)));

DEVI int imax(int a, int b) { return a > b ? a : b; }

// value of left lane (x-1) within 16-lane row; x==0 -> 0  (row_shr:1)
DEVI float dppL(float v) {
    return __int_as_float(
        __builtin_amdgcn_update_dpp(0, __float_as_int(v), 0x111, 0xF, 0xF, true));
}
// value of right lane (x+1); x==15 -> 0  (row_shl:1)
DEVI float dppR(float v) {
    return __int_as_float(
        __builtin_amdgcn_update_dpp(0, __float_as_int(v), 0x101, 0xF, 0xF, true));
}

// --------------------------- setup kernel ----------------------------------
// blocks 0..15: codebook normalize + fp16 hi/lo split
// blocks 16..159: weight repack  wT[k][q8][ic][k9][o2], oc=(q8>>2)*16+(q8&3)*4+o2
// block 160: bicubic U matrices (f64 math) + zero lossAcc/hist
// blocks 161..1184: zero fhat
__global__ void __launch_bounds__(256) k_setup(const float* __restrict__ cb,
                                               const float* __restrict__ pw,
                                               _Float16* __restrict__ cbh,
                                               _Float16* __restrict__ cbl,
                                               float* __restrict__ wT,
                                               float* __restrict__ um,
                                               float* __restrict__ fhat,
                                               float* __restrict__ lossAcc) {
    int blk = blockIdx.x, tid = threadIdx.x;
    if (blk < 16) {
        int r = blk * 256 + tid;
        const float* src = cb + r * 32;
        float v[32];
        float ss = 0.f;
#pragma unroll
        for (int j = 0; j < 32; ++j) { v[j] = src[j]; ss += v[j] * v[j]; }
        float n = fmaxf(sqrtf(ss), 1e-12f);
#pragma unroll
        for (int j = 0; j < 32; ++j) {
            float x = v[j] / n;
            _Float16 h = (_Float16)x;
            cbh[r * 32 + j] = h;
            cbl[r * 32 + j] = (_Float16)(x - (float)h);
        }
    } else if (blk < 160) {
        int e = (blk - 16) * 256 + tid;             // < 36864
        int k = e / 9216, rem = e % 9216;
        int q8 = rem / 1152, rem2 = rem % 1152;
        int ic = rem2 / 36, r3 = rem2 % 36;
        int k9 = r3 / 4, o2 = r3 % 4;
        int oc = (q8 >> 2) * 16 + (q8 & 3) * 4 + o2;
        int ky = k9 / 3, kx = k9 % 3;
        wT[e] = pw[(((k * 32 + oc) * 32 + ic) * 3 + ky) * 3 + kx];
    } else if (blk == 160) {
        if (tid < 144) {
            const int pns[9] = {1, 2, 3, 4, 5, 6, 8, 10, 13};
            int si = tid / 16, y = tid % 16, pn = pns[si];
            double scale = (double)pn / 16.0;
            double src = ((double)y + 0.5) * scale - 0.5;
            double fl = floor(src);
            int i0 = (int)fl;
            double f = src - fl;
            float row[13];
            for (int j = 0; j < pn; ++j) row[j] = 0.f;
            const double a = -0.75;
#pragma unroll
            for (int off = -1; off <= 2; ++off) {
                double t2 = fabs(f - (double)off);
                double wgt;
                if (t2 <= 1.0)      wgt = ((a + 2.0) * t2 - (a + 3.0)) * t2 * t2 + 1.0;
                else if (t2 < 2.0)  wgt = (((t2 - 5.0) * t2 + 8.0) * t2 - 4.0) * a;
                else                wgt = 0.0;
                int j = i0 + off;
                j = j < 0 ? 0 : (j > pn - 1 ? pn - 1 : j);
                row[j] = (float)((double)row[j] + wgt);   // numpy f32 += f64
            }
            for (int j = 0; j < pn; ++j) um[si * 256 + y * pn + j] = row[j];
        } else {
            // zero lossAcc (16 f) + hist (4096 i32), contiguous
            for (int i = tid - 144; i < 4112; i += 112) ((int*)lossAcc)[i] = 0;
        }
    } else {
        int i = (blk - 161) * 1024 + tid * 4;
        float4 z = {0.f, 0.f, 0.f, 0.f};
        *(float4*)(fhat + i) = z;
    }
}

// ----------------------- per-scale kernels ---------------------------------

// area downsample of (f_input - f_hat) -> token-major fp16 hi/lo [t*32+c];
// pads tokens T..Tp with zeros
template <int PN>
__global__ void __launch_bounds__(256) k_down(const float* __restrict__ fin,
                                              const float* __restrict__ fhat,
                                              _Float16* __restrict__ xh,
                                              _Float16* __restrict__ xl) {
    constexpr int T = 128 * PN * PN;
    constexpr int Tp = ((T + 511) / 512) * 512;
    int id = blockIdx.x * 256 + threadIdx.x;
    if (id >= 32 * Tp) return;
    int t = id >> 5, c = id & 31;
    if (t >= T) { xh[id] = (_Float16)0.f; xl[id] = (_Float16)0.f; return; }
    int b = t / (PN * PN), r = t % (PN * PN), oy = r / PN, ox = r % PN;
    int sy = oy * 16 / PN, ey = ((oy + 1) * 16 + PN - 1) / PN;
    int sx = ox * 16 / PN, ex = ((ox + 1) * 16 + PN - 1) / PN;
    float wy = 1.f / (float)(ey - sy);
    float wx = 1.f / (float)(ex - sx);
    const float* pi = fin + b * 8192 + c * 256;
    const float* ph = fhat + b * 8192 + c * 256;
    float s = 0.f;
    if constexpr (PN == 1 || PN == 2 || PN == 4) {
        // aligned W x W window, W = 16/PN multiple of 4: float4 loads,
        // scalar accumulation order preserved exactly
        constexpr int W = 16 / PN;
        const float4* p4 = (const float4*)(pi + sy * 16 + sx);
        const float4* h4 = (const float4*)(ph + sy * 16 + sx);
#pragma unroll
        for (int y = 0; y < W; ++y)
#pragma unroll
            for (int xx = 0; xx < W / 4; ++xx) {
                float4 a = p4[y * 4 + xx], b4 = h4[y * 4 + xx];
                s += a.x - b4.x;
                s += a.y - b4.y;
                s += a.z - b4.z;
                s += a.w - b4.w;
            }
    } else {
        for (int y = sy; y < ey; ++y)
            for (int x = sx; x < ex; ++x)
                s += pi[y * 16 + x] - ph[y * 16 + x];
    }
    float v = s * (wy * wx);
    _Float16 h = (_Float16)v;
    xh[id] = h;
    xl[id] = (_Float16)(v - (float)h);
}

// MFMA cosine argmax, LDS-free. Block = 4 independent waves; wave = 128
// tokens (8 M-tiles). A = codes (regs, direct global load, L1-hot across
// waves), B = tokens => lane holds 4 codes of ONE token:
//   token = lane&15, code = cbase + nt*16 + (lane>>4)*4 + r.
// Winner tracked as packed i32 key: (score_bits & ~(CPS-1)) | (CPS-1-local),
// signed-int max (positive floats order as ints; argmax is always positive).
// Per-(seg,token) winner -> PLAIN coalesced u32 store bestp[seg*Tp + token].
template <int PN, int SEG>
__global__ void __launch_bounds__(256, 2) k_quant(
        const half8* __restrict__ xh, const half8* __restrict__ xl,
        const half8* __restrict__ cbh8, const half8* __restrict__ cbl8,
        unsigned* __restrict__ bestp) {
    constexpr int T = 128 * PN * PN;
    constexpr int Tp = ((T + 511) / 512) * 512;
    constexpr int TB = Tp / 512;
    constexpr int CPS = 4096 / SEG;                 // codes per segment (=128)
    static_assert(CPS == 128, "reg-resident sweep sized for CPS==128");

    int tid = threadIdx.x;
    int bt = blockIdx.x % TB, seg = blockIdx.x / TB;
    int wv = tid >> 6, lane = tid & 63;
    int n0 = lane & 15, g = lane >> 4;
    int tokbase = bt * 512 + wv * 128;
    int cbase = seg * CPS;

    // token fragments (A-side data)
    half8 ah[8], al[8];
#pragma unroll
    for (int mt = 0; mt < 8; ++mt) {
        int tok = tokbase + mt * 16 + n0;
        ah[mt] = xh[tok * 4 + g];
        al[mt] = xl[tok * 4 + g];
    }
    // code fragments (all 128 codes of this segment, in regs)
    half8 bh[8], bl[8];
#pragma unroll
    for (int nt = 0; nt < 8; ++nt) {
        int code = cbase + nt * 16 + n0;
        bh[nt] = cbh8[code * 4 + g];
        bl[nt] = cbl8[code * 4 + g];
    }

    int mx[8];
#pragma unroll
    for (int mt = 0; mt < 8; ++mt) mx[mt] = (int)0x80000000;

    const floatx4 z4 = {0.f, 0.f, 0.f, 0.f};
    const int KMASK = ~(CPS - 1);                   // trunc mask (idx bits low)
    int lowg = CPS - 1 - g * 4;                     // per-lane idx-bit base
#pragma unroll
    for (int nt = 0; nt < 8; ++nt) {
        int lowb = lowg - nt * 16;                  // key low bits for r=0
#pragma unroll
        for (int mt = 0; mt < 8; ++mt) {
            floatx4 c;
            c = __builtin_amdgcn_mfma_f32_16x16x32_f16(bh[nt], ah[mt], z4, 0, 0, 0);
            c = __builtin_amdgcn_mfma_f32_16x16x32_f16(bl[nt], ah[mt], c,  0, 0, 0);
            c = __builtin_amdgcn_mfma_f32_16x16x32_f16(bh[nt], al[mt], c,  0, 0, 0);
            int k0 = (__float_as_int(c[0]) & KMASK) | (lowb - 0);
            int k1 = (__float_as_int(c[1]) & KMASK) | (lowb - 1);
            int k2 = (__float_as_int(c[2]) & KMASK) | (lowb - 2);
            int k3 = (__float_as_int(c[3]) & KMASK) | (lowb - 3);
            mx[mt] = imax(mx[mt], imax(k0, k1));   // -> v_max3_i32
            mx[mt] = imax(mx[mt], imax(k2, k3));
        }
    }

    // reduce across the 4 lanes sharing a token (g = lane>>4), then store
    unsigned* dst = bestp + (size_t)seg * Tp;
#pragma unroll
    for (int mt = 0; mt < 8; ++mt) {
        int k = mx[mt];
        k = imax(k, __shfl_xor(k, 16, 64));
        k = imax(k, __shfl_xor(k, 32, 64));
        if (g == (mt >> 1))                          // static mx index, 16 lanes
            dst[tokbase + mt * 16 + n0] = (unsigned)k;
    }
}

// SEG-merge argmax + gather + bicubic (6 rows) + 3x3 conv (phi) + fhat + loss.
// grid 1024 = (img, quarter of 4 rows, oc-half); 256 thr = 4 waves x 64 px.
// S_hu overlays h0 (h0 dead after y-pass).  Conv core: DPP x-neighbors,
// repacked contiguous weights, 4 oc/thread.
template <int PN, int SEG, int K, bool LAST>
__global__ void __launch_bounds__(256) k_upconv(
        const float* __restrict__ fin, float* __restrict__ fhat,
        const float* __restrict__ cbook,
        const unsigned* __restrict__ bestp,
        const float* __restrict__ wT, const float* __restrict__ phib,
        const float* __restrict__ um, float* __restrict__ lossAcc,
        int* __restrict__ hist, float* __restrict__ dout) {
    constexpr int NT = PN * PN;
    constexpr int T = 128 * NT;
    constexpr int Tp = ((T + 511) / 512) * 512;
    constexpr int CPS = 4096 / SEG;
    constexpr int RA = (PN < 16 && NT * 32 > 4096) ? NT * 32 : 4096;
    __shared__ __align__(16) float regionA[RA];          // h0, then S_hu (4096)
    __shared__ float hu1[(PN < 16) ? 32 * 6 * PN : 1];   // [c][rr][i]
    __shared__ float Us[(PN < 16) ? 16 * PN : 1];
    __shared__ int idxs[NT];
    __shared__ float red[4];
    float* S_hu = regionA;
    float* h0 = regionA;

    int img = blockIdx.x >> 3, q = (blockIdx.x >> 1) & 3, och = blockIdx.x & 1;
    int y0 = q * 4;
    int tid = threadIdx.x;

    // SEG-way merge of per-segment winners (coalesced per segment pass);
    // signed compare; strict > keeps the EARLIEST (smallest-idx) segment.
    for (int e = tid; e < NT; e += 256) {
        int tok = img * NT + e;
        int k = (int)bestp[tok];
        int ws = 0;
#pragma unroll
        for (int s = 1; s < SEG; ++s) {
            int o = (int)bestp[(size_t)s * Tp + tok];
            bool gt = o > k;
            k = gt ? o : k;
            ws = gt ? s : ws;
        }
        idxs[e] = ws * CPS + (CPS - 1 - (k & (CPS - 1)));
    }
    if (PN < 16)
        for (int e = tid; e < 16 * PN; e += 256) Us[e] = um[e];
    __syncthreads();

    if (PN == 16) {
        if (LAST && och == 0 && tid < 64)    // this quarter's 64 tokens
            atomicAdd(hist + idxs[y0 * 16 + tid], 1);
        // direct gather into S_hu rows rr+1 (gy = y0-1+rr), zero out-of-image
        for (int e = tid; e < 3072; e += 256) {
            int c = e / 96, r = e % 96;
            int rr = r >> 4, x = r & 15;
            int gy = y0 - 1 + rr;
            float v = 0.f;
            if (gy >= 0 && gy <= 15) v = cbook[idxs[gy * 16 + x] * 32 + c];
            S_hu[c * 128 + (rr + 1) * 16 + x] = v;
        }
    } else {
        for (int e = tid; e < NT * 32; e += 256) {       // h0[tok][c]
            int tk = e >> 5, c = e & 31;
            h0[e] = cbook[idxs[tk] * 32 + c];
        }
        __syncthreads();
        // y-pass (6 needed rows): hu1[c][rr][i] = sum_j U[gy][j]*h0[j*PN+i][c]
        for (int e = tid; e < 6 * PN * 32; e += 256) {
            int c = e & 31, rest = e >> 5;
            int rr = rest / PN, i = rest % PN;
            int gy = y0 - 1 + rr;
            float s = 0.f;
            if (gy >= 0 && gy <= 15)
                for (int j = 0; j < PN; ++j)
                    s += Us[gy * PN + j] * h0[(j * PN + i) * 32 + c];
            hu1[(c * 6 + rr) * PN + i] = s;
        }
        __syncthreads();
        // x-pass -> S_hu (overwrites h0 region; h0 dead)
        for (int e = tid; e < 3072; e += 256) {
            int c = e / 96, r = e % 96;
            int rr = r >> 4, x = r & 15;
            int gy = y0 - 1 + rr;
            float s = 0.f;
            if (gy >= 0 && gy <= 15)
                for (int i = 0; i < PN; ++i)
                    s += Us[x * PN + i] * hu1[(c * 6 + rr) * PN + i];
            S_hu[c * 128 + (rr + 1) * 16 + x] = s;
        }
    }
    __syncthreads();

    // ---- conv core: DPP x-neighbors, 4 oc/thread ----
    int px = tid & 63;
    int ocg = __builtin_amdgcn_readfirstlane(tid >> 6);  // wave id, uniform
    int yo = px >> 4, x = px & 15;
    int y = y0 + yo;
    int ry = yo + 2;                                     // center row in S_hu
    float acc[4] = {0.f, 0.f, 0.f, 0.f};
    const float* wk = wT + K * 9216 + (och * 4 + ocg) * 1152;  // [ic][k9][4]
#pragma unroll 4
    for (int ic = 0; ic < 32; ++ic) {
        int a = ic * 128 + ry * 16 + x;
        float cm = S_hu[a - 16], cc = S_hu[a], cp = S_hu[a + 16];
        float lm = dppL(cm), lc = dppL(cc), lp = dppL(cp);
        float rm = dppR(cm), rc = dppR(cc), rp = dppR(cp);
        const float* w = wk + ic * 36;
#pragma unroll
        for (int o = 0; o < 4; ++o) {
            float s = acc[o];
            s = fmaf(w[o],      lm, s);   // ky=0 (row y-1): x-1, x, x+1
            s = fmaf(w[4 + o],  cm, s);
            s = fmaf(w[8 + o],  rm, s);
            s = fmaf(w[12 + o], lc, s);   // ky=1
            s = fmaf(w[16 + o], cc, s);
            s = fmaf(w[20 + o], rc, s);
            s = fmaf(w[24 + o], lp, s);   // ky=2
            s = fmaf(w[28 + o], cp, s);
            s = fmaf(w[32 + o], rp, s);
            acc[o] = s;
        }
    }

    // epilogue: 4 oc per thread at its pixel
    float ss = 0.f;
    {
        int oc0 = och * 16 + ocg * 4;
        int gbase = img * 8192 + oc0 * 256 + y * 16 + x;
        const float* bias = phib + K * 32 + oc0;
#pragma unroll
        for (int oi = 0; oi < 4; ++oi) {
            float conv = acc[oi] + bias[oi];
            float hval = 0.5f * S_hu[(oc0 + oi) * 128 + ry * 16 + x] + 0.5f * conv;
            float fh = fhat[gbase + oi * 256] + hval;
            fhat[gbase + oi * 256] = fh;
            if (LAST) dout[gbase + oi * 256] = fh;
            float d = fh - fin[gbase + oi * 256];
            ss = fmaf(d, d, ss);
        }
    }
    int lane = tid & 63;
#pragma unroll
    for (int m = 1; m < 64; m <<= 1) ss += __shfl_xor(ss, m, 64);
    if (lane == 0) red[tid >> 6] = ss;
    __syncthreads();
    if (tid == 0) atomicAdd(lossAcc, red[0] + red[1] + red[2] + red[3]);
}

__global__ void __launch_bounds__(256) k_final(const float* __restrict__ lossAcc,
                                               const int* __restrict__ hist,
                                               float* __restrict__ out) {
    __shared__ float red[256];
    int tid = threadIdx.x;
    float s = 0.f;
    for (int i = tid; i < 4096; i += 256) {
        float p = (float)hist[i] * (1.f / 32768.f);
        s += p * logf(p + 1e-10f);
    }
    red[tid] = s;
    __syncthreads();
    for (int k = 128; k > 0; k >>= 1) {
        if (tid < k) red[tid] += red[tid + k];
        __syncthreads();
    }
    if (tid == 0) {
        out[1048577] = expf(-red[0]);
        float L = 0.f;
        for (int si = 0; si < 10; ++si) L += lossAcc[si];
        out[1048576] = L * 1.25f / 1048576.f * 0.1f;
    }
}

// ------------------------------ launch -------------------------------------

extern "C" void kernel_launch(void* const* d_in, const int* in_sizes, int n_in,
                              void* d_out, int out_size, void* d_ws, size_t ws_size,
                              hipStream_t stream) {
    const float* f_in  = (const float*)d_in[0];   // [128,32,16,16]
    const float* cbook = (const float*)d_in[1];   // [4096,32]
    const float* phiw  = (const float*)d_in[2];   // [4,32,32,3,3]
    const float* phib  = (const float*)d_in[3];   // [4,32]
    float* out = (float*)d_out;
    char* base = (char*)d_ws;

    float* fhat    = (float*)(base);                       // 4,194,304 B
    float* lossAcc = (float*)(base + 4194304);             // 64 B
    int*   hist    = (int*)  (base + 4194368);             // 16,384 B
    float* wT      = (float*)(base + 4210752);             // 147,456 B
    float* um      = (float*)(base + 4358208);             // 9,216 B
    _Float16* cbh  = (_Float16*)(base + 4367424);          // 262,144 B
    _Float16* cbl  = (_Float16*)(base + 4629568);          // 262,144 B
    _Float16* xh   = (_Float16*)(base + 4891712);          // 2,097,152 B
    _Float16* xl   = (_Float16*)(base + 6988864);          // 2,097,152 B
    unsigned* bestp = (unsigned*)(base + 9086016);         // 4,194,304 B (32 segs)

    k_setup<<<1185, 256, 0, stream>>>(cbook, phiw, cbh, cbl, wT, um, fhat, lossAcc);

#define SCALE(SI, PN, K, LAST)                                                         \
    {                                                                                  \
        constexpr int T = 128 * PN * PN;                                               \
        constexpr int Tp = ((T + 511) / 512) * 512;                                    \
        constexpr int TB = Tp / 512;                                                   \
        k_down<PN><<<(Tp * 32) / 256, 256, 0, stream>>>(f_in, fhat, xh, xl);           \
        k_quant<PN, 32><<<TB * 32, 256, 0, stream>>>(                                  \
            (const half8*)xh, (const half8*)xl, (const half8*)cbh,                     \
            (const half8*)cbl, bestp);                                                 \
        k_upconv<PN, 32, K, LAST><<<1024, 256, 0, stream>>>(                           \
            f_in, fhat, cbook, bestp, wT, phib, um + SI * 256, lossAcc + SI, hist,     \
            out);                                                                      \
    }
    SCALE(0, 1, 0, false);
    SCALE(1, 2, 0, false);
    SCALE(2, 3, 0, false);
    SCALE(3, 4, 1, false);
    SCALE(4, 5, 1, false);
    SCALE(5, 6, 2, false);
    SCALE(6, 8, 2, false);
    SCALE(7, 10, 2, false);
    SCALE(8, 13, 3, false);
    SCALE(9, 16, 3, true);
#undef SCALE
    k_final<<<1, 256, 0, stream>>>(lossAcc, hist, out);
}

// Round 4
// 581.714 us; speedup vs baseline: 1.1836x; 1.1836x over previous
//
#include <hip/hip_runtime.h>
#include <stdint.h>
#include <math.h>

// ---------------------------------------------------------------------------
// MultiScaleResidualQuantizer3D  (B=128, C=32, HW=16, N_E=4096, 10 scales)
// Round 17: fix round-16's register spill in LDS-free k_quant.
//   Round-16 post-mortem: WRITE_SIZE 4MB->121MB, FETCH 4->45MB on
//   k_quant<16,32> = scratch spill (fragments 128 VGPR + mx + misc > 128
//   allocated); k_quant<1,32>'s 121us at zero-counters = first-dispatch
//   scratch-buffer allocation artifact.
//   Fix: tokens stay resident (ah/al, 64 VGPR, reused by all 8 code tiles);
//   code fragments bh/bl loaded INSIDE the nt loop (#pragma unroll 1) so only
//   ~8-16 VGPR of codes live at once. ~105 VGPR live -> no spill, still
//   LDS-free and barrier-free (fully independent waves).
// Carried from round 14/15:
//   - MFMA swapped (A=codes, B=tokens), packed i32 keys + v_max3_i32,
//     4-lane shfl epilogue, bestp = u32[seg][tok], upconv 32-way merge.
//   - k_down float4 pooling for PN in {1,2,4} (exact scalar accum order).
//   - PHI_IDX = [0,0,0,1,1,2,2,2,3,3] (exact np.linspace tie resolution)
// ---------------------------------------------------------------------------

#define DEVI __device__ __forceinline__

static constexpr int NE = 4096;

typedef _Float16 half8 __attribute__((ext_vector_type(8)));
typedef float floatx4 __attribute__((ext_vector_type(4)));

DEVI int imax(int a, int b) { return a > b ? a : b; }

// value of left lane (x-1) within 16-lane row; x==0 -> 0  (row_shr:1)
DEVI float dppL(float v) {
    return __int_as_float(
        __builtin_amdgcn_update_dpp(0, __float_as_int(v), 0x111, 0xF, 0xF, true));
}
// value of right lane (x+1); x==15 -> 0  (row_shl:1)
DEVI float dppR(float v) {
    return __int_as_float(
        __builtin_amdgcn_update_dpp(0, __float_as_int(v), 0x101, 0xF, 0xF, true));
}

// --------------------------- setup kernel ----------------------------------
// blocks 0..15: codebook normalize + fp16 hi/lo split
// blocks 16..159: weight repack  wT[k][q8][ic][k9][o2], oc=(q8>>2)*16+(q8&3)*4+o2
// block 160: bicubic U matrices (f64 math) + zero lossAcc/hist
// blocks 161..1184: zero fhat
__global__ void __launch_bounds__(256) k_setup(const float* __restrict__ cb,
                                               const float* __restrict__ pw,
                                               _Float16* __restrict__ cbh,
                                               _Float16* __restrict__ cbl,
                                               float* __restrict__ wT,
                                               float* __restrict__ um,
                                               float* __restrict__ fhat,
                                               float* __restrict__ lossAcc) {
    int blk = blockIdx.x, tid = threadIdx.x;
    if (blk < 16) {
        int r = blk * 256 + tid;
        const float* src = cb + r * 32;
        float v[32];
        float ss = 0.f;
#pragma unroll
        for (int j = 0; j < 32; ++j) { v[j] = src[j]; ss += v[j] * v[j]; }
        float n = fmaxf(sqrtf(ss), 1e-12f);
#pragma unroll
        for (int j = 0; j < 32; ++j) {
            float x = v[j] / n;
            _Float16 h = (_Float16)x;
            cbh[r * 32 + j] = h;
            cbl[r * 32 + j] = (_Float16)(x - (float)h);
        }
    } else if (blk < 160) {
        int e = (blk - 16) * 256 + tid;             // < 36864
        int k = e / 9216, rem = e % 9216;
        int q8 = rem / 1152, rem2 = rem % 1152;
        int ic = rem2 / 36, r3 = rem2 % 36;
        int k9 = r3 / 4, o2 = r3 % 4;
        int oc = (q8 >> 2) * 16 + (q8 & 3) * 4 + o2;
        int ky = k9 / 3, kx = k9 % 3;
        wT[e] = pw[(((k * 32 + oc) * 32 + ic) * 3 + ky) * 3 + kx];
    } else if (blk == 160) {
        if (tid < 144) {
            const int pns[9] = {1, 2, 3, 4, 5, 6, 8, 10, 13};
            int si = tid / 16, y = tid % 16, pn = pns[si];
            double scale = (double)pn / 16.0;
            double src = ((double)y + 0.5) * scale - 0.5;
            double fl = floor(src);
            int i0 = (int)fl;
            double f = src - fl;
            float row[13];
            for (int j = 0; j < pn; ++j) row[j] = 0.f;
            const double a = -0.75;
#pragma unroll
            for (int off = -1; off <= 2; ++off) {
                double t2 = fabs(f - (double)off);
                double wgt;
                if (t2 <= 1.0)      wgt = ((a + 2.0) * t2 - (a + 3.0)) * t2 * t2 + 1.0;
                else if (t2 < 2.0)  wgt = (((t2 - 5.0) * t2 + 8.0) * t2 - 4.0) * a;
                else                wgt = 0.0;
                int j = i0 + off;
                j = j < 0 ? 0 : (j > pn - 1 ? pn - 1 : j);
                row[j] = (float)((double)row[j] + wgt);   // numpy f32 += f64
            }
            for (int j = 0; j < pn; ++j) um[si * 256 + y * pn + j] = row[j];
        } else {
            // zero lossAcc (16 f) + hist (4096 i32), contiguous
            for (int i = tid - 144; i < 4112; i += 112) ((int*)lossAcc)[i] = 0;
        }
    } else {
        int i = (blk - 161) * 1024 + tid * 4;
        float4 z = {0.f, 0.f, 0.f, 0.f};
        *(float4*)(fhat + i) = z;
    }
}

// ----------------------- per-scale kernels ---------------------------------

// area downsample of (f_input - f_hat) -> token-major fp16 hi/lo [t*32+c];
// pads tokens T..Tp with zeros
template <int PN>
__global__ void __launch_bounds__(256) k_down(const float* __restrict__ fin,
                                              const float* __restrict__ fhat,
                                              _Float16* __restrict__ xh,
                                              _Float16* __restrict__ xl) {
    constexpr int T = 128 * PN * PN;
    constexpr int Tp = ((T + 511) / 512) * 512;
    int id = blockIdx.x * 256 + threadIdx.x;
    if (id >= 32 * Tp) return;
    int t = id >> 5, c = id & 31;
    if (t >= T) { xh[id] = (_Float16)0.f; xl[id] = (_Float16)0.f; return; }
    int b = t / (PN * PN), r = t % (PN * PN), oy = r / PN, ox = r % PN;
    int sy = oy * 16 / PN, ey = ((oy + 1) * 16 + PN - 1) / PN;
    int sx = ox * 16 / PN, ex = ((ox + 1) * 16 + PN - 1) / PN;
    float wy = 1.f / (float)(ey - sy);
    float wx = 1.f / (float)(ex - sx);
    const float* pi = fin + b * 8192 + c * 256;
    const float* ph = fhat + b * 8192 + c * 256;
    float s = 0.f;
    if constexpr (PN == 1 || PN == 2 || PN == 4) {
        // aligned W x W window, W = 16/PN multiple of 4: float4 loads,
        // scalar accumulation order preserved exactly
        constexpr int W = 16 / PN;
        const float4* p4 = (const float4*)(pi + sy * 16 + sx);
        const float4* h4 = (const float4*)(ph + sy * 16 + sx);
#pragma unroll
        for (int y = 0; y < W; ++y)
#pragma unroll
            for (int xx = 0; xx < W / 4; ++xx) {
                float4 a = p4[y * 4 + xx], b4 = h4[y * 4 + xx];
                s += a.x - b4.x;
                s += a.y - b4.y;
                s += a.z - b4.z;
                s += a.w - b4.w;
            }
    } else {
        for (int y = sy; y < ey; ++y)
            for (int x = sx; x < ex; ++x)
                s += pi[y * 16 + x] - ph[y * 16 + x];
    }
    float v = s * (wy * wx);
    _Float16 h = (_Float16)v;
    xh[id] = h;
    xl[id] = (_Float16)(v - (float)h);
}

// MFMA cosine argmax, LDS-free. Block = 4 independent waves; wave = 128
// tokens (8 M-tiles). A = codes (direct global load, L1/L2-hot across
// waves), B = tokens => lane holds 4 codes of ONE token:
//   token = lane&15, code = cbase + nt*16 + (lane>>4)*4 + r.
// Tokens stay register-resident (64 VGPR); code fragments are loaded inside
// the nt loop (#pragma unroll 1) so only one tile is live -> no spill.
// Winner tracked as packed i32 key: (score_bits & ~(CPS-1)) | (CPS-1-local),
// signed-int max (positive floats order as ints; argmax is always positive).
// Per-(seg,token) winner -> PLAIN coalesced u32 store bestp[seg*Tp + token].
template <int PN, int SEG>
__global__ void __launch_bounds__(256, 2) k_quant(
        const half8* __restrict__ xh, const half8* __restrict__ xl,
        const half8* __restrict__ cbh8, const half8* __restrict__ cbl8,
        unsigned* __restrict__ bestp) {
    constexpr int T = 128 * PN * PN;
    constexpr int Tp = ((T + 511) / 512) * 512;
    constexpr int TB = Tp / 512;
    constexpr int CPS = 4096 / SEG;                 // codes per segment (=128)
    static_assert(CPS == 128, "reg-resident sweep sized for CPS==128");

    int tid = threadIdx.x;
    int bt = blockIdx.x % TB, seg = blockIdx.x / TB;
    int wv = tid >> 6, lane = tid & 63;
    int n0 = lane & 15, g = lane >> 4;
    int tokbase = bt * 512 + wv * 128;
    int cbase = seg * CPS;

    // token fragments (A-side data), resident across the whole sweep
    half8 ah[8], al[8];
#pragma unroll
    for (int mt = 0; mt < 8; ++mt) {
        int tok = tokbase + mt * 16 + n0;
        ah[mt] = xh[tok * 4 + g];
        al[mt] = xl[tok * 4 + g];
    }

    int mx[8];
#pragma unroll
    for (int mt = 0; mt < 8; ++mt) mx[mt] = (int)0x80000000;

    const floatx4 z4 = {0.f, 0.f, 0.f, 0.f};
    const int KMASK = ~(CPS - 1);                   // trunc mask (idx bits low)
    int lowg = CPS - 1 - g * 4;                     // per-lane idx-bit base
    // one code tile live at a time (8-16 VGPR): do NOT unroll, or the
    // compiler hoists all 16 loads and recreates round-16's spill.
#pragma unroll 1
    for (int nt = 0; nt < 8; ++nt) {
        int code = cbase + nt * 16 + n0;
        half8 bh = cbh8[code * 4 + g];
        half8 bl = cbl8[code * 4 + g];
        int lowb = lowg - nt * 16;                  // key low bits for r=0
#pragma unroll
        for (int mt = 0; mt < 8; ++mt) {
            floatx4 c;
            c = __builtin_amdgcn_mfma_f32_16x16x32_f16(bh, ah[mt], z4, 0, 0, 0);
            c = __builtin_amdgcn_mfma_f32_16x16x32_f16(bl, ah[mt], c,  0, 0, 0);
            c = __builtin_amdgcn_mfma_f32_16x16x32_f16(bh, al[mt], c,  0, 0, 0);
            int k0 = (__float_as_int(c[0]) & KMASK) | (lowb - 0);
            int k1 = (__float_as_int(c[1]) & KMASK) | (lowb - 1);
            int k2 = (__float_as_int(c[2]) & KMASK) | (lowb - 2);
            int k3 = (__float_as_int(c[3]) & KMASK) | (lowb - 3);
            mx[mt] = imax(mx[mt], imax(k0, k1));   // -> v_max3_i32
            mx[mt] = imax(mx[mt], imax(k2, k3));
        }
    }

    // reduce across the 4 lanes sharing a token (g = lane>>4), then store
    unsigned* dst = bestp + (size_t)seg * Tp;
#pragma unroll
    for (int mt = 0; mt < 8; ++mt) {
        int k = mx[mt];
        k = imax(k, __shfl_xor(k, 16, 64));
        k = imax(k, __shfl_xor(k, 32, 64));
        if (g == (mt >> 1))                          // static mx index, 16 lanes
            dst[tokbase + mt * 16 + n0] = (unsigned)k;
    }
}

// SEG-merge argmax + gather + bicubic (6 rows) + 3x3 conv (phi) + fhat + loss.
// grid 1024 = (img, quarter of 4 rows, oc-half); 256 thr = 4 waves x 64 px.
// S_hu overlays h0 (h0 dead after y-pass).  Conv core: DPP x-neighbors,
// repacked contiguous weights, 4 oc/thread.
template <int PN, int SEG, int K, bool LAST>
__global__ void __launch_bounds__(256) k_upconv(
        const float* __restrict__ fin, float* __restrict__ fhat,
        const float* __restrict__ cbook,
        const unsigned* __restrict__ bestp,
        const float* __restrict__ wT, const float* __restrict__ phib,
        const float* __restrict__ um, float* __restrict__ lossAcc,
        int* __restrict__ hist, float* __restrict__ dout) {
    constexpr int NT = PN * PN;
    constexpr int T = 128 * NT;
    constexpr int Tp = ((T + 511) / 512) * 512;
    constexpr int CPS = 4096 / SEG;
    constexpr int RA = (PN < 16 && NT * 32 > 4096) ? NT * 32 : 4096;
    __shared__ __align__(16) float regionA[RA];          // h0, then S_hu (4096)
    __shared__ float hu1[(PN < 16) ? 32 * 6 * PN : 1];   // [c][rr][i]
    __shared__ float Us[(PN < 16) ? 16 * PN : 1];
    __shared__ int idxs[NT];
    __shared__ float red[4];
    float* S_hu = regionA;
    float* h0 = regionA;

    int img = blockIdx.x >> 3, q = (blockIdx.x >> 1) & 3, och = blockIdx.x & 1;
    int y0 = q * 4;
    int tid = threadIdx.x;

    // SEG-way merge of per-segment winners (coalesced per segment pass);
    // signed compare; strict > keeps the EARLIEST (smallest-idx) segment.
    for (int e = tid; e < NT; e += 256) {
        int tok = img * NT + e;
        int k = (int)bestp[tok];
        int ws = 0;
#pragma unroll
        for (int s = 1; s < SEG; ++s) {
            int o = (int)bestp[(size_t)s * Tp + tok];
            bool gt = o > k;
            k = gt ? o : k;
            ws = gt ? s : ws;
        }
        idxs[e] = ws * CPS + (CPS - 1 - (k & (CPS - 1)));
    }
    if (PN < 16)
        for (int e = tid; e < 16 * PN; e += 256) Us[e] = um[e];
    __syncthreads();

    if (PN == 16) {
        if (LAST && och == 0 && tid < 64)    // this quarter's 64 tokens
            atomicAdd(hist + idxs[y0 * 16 + tid], 1);
        // direct gather into S_hu rows rr+1 (gy = y0-1+rr), zero out-of-image
        for (int e = tid; e < 3072; e += 256) {
            int c = e / 96, r = e % 96;
            int rr = r >> 4, x = r & 15;
            int gy = y0 - 1 + rr;
            float v = 0.f;
            if (gy >= 0 && gy <= 15) v = cbook[idxs[gy * 16 + x] * 32 + c];
            S_hu[c * 128 + (rr + 1) * 16 + x] = v;
        }
    } else {
        for (int e = tid; e < NT * 32; e += 256) {       // h0[tok][c]
            int tk = e >> 5, c = e & 31;
            h0[e] = cbook[idxs[tk] * 32 + c];
        }
        __syncthreads();
        // y-pass (6 needed rows): hu1[c][rr][i] = sum_j U[gy][j]*h0[j*PN+i][c]
        for (int e = tid; e < 6 * PN * 32; e += 256) {
            int c = e & 31, rest = e >> 5;
            int rr = rest / PN, i = rest % PN;
            int gy = y0 - 1 + rr;
            float s = 0.f;
            if (gy >= 0 && gy <= 15)
                for (int j = 0; j < PN; ++j)
                    s += Us[gy * PN + j] * h0[(j * PN + i) * 32 + c];
            hu1[(c * 6 + rr) * PN + i] = s;
        }
        __syncthreads();
        // x-pass -> S_hu (overwrites h0 region; h0 dead)
        for (int e = tid; e < 3072; e += 256) {
            int c = e / 96, r = e % 96;
            int rr = r >> 4, x = r & 15;
            int gy = y0 - 1 + rr;
            float s = 0.f;
            if (gy >= 0 && gy <= 15)
                for (int i = 0; i < PN; ++i)
                    s += Us[x * PN + i] * hu1[(c * 6 + rr) * PN + i];
            S_hu[c * 128 + (rr + 1) * 16 + x] = s;
        }
    }
    __syncthreads();

    // ---- conv core: DPP x-neighbors, 4 oc/thread ----
    int px = tid & 63;
    int ocg = __builtin_amdgcn_readfirstlane(tid >> 6);  // wave id, uniform
    int yo = px >> 4, x = px & 15;
    int y = y0 + yo;
    int ry = yo + 2;                                     // center row in S_hu
    float acc[4] = {0.f, 0.f, 0.f, 0.f};
    const float* wk = wT + K * 9216 + (och * 4 + ocg) * 1152;  // [ic][k9][4]
#pragma unroll 4
    for (int ic = 0; ic < 32; ++ic) {
        int a = ic * 128 + ry * 16 + x;
        float cm = S_hu[a - 16], cc = S_hu[a], cp = S_hu[a + 16];
        float lm = dppL(cm), lc = dppL(cc), lp = dppL(cp);
        float rm = dppR(cm), rc = dppR(cc), rp = dppR(cp);
        const float* w = wk + ic * 36;
#pragma unroll
        for (int o = 0; o < 4; ++o) {
            float s = acc[o];
            s = fmaf(w[o],      lm, s);   // ky=0 (row y-1): x-1, x, x+1
            s = fmaf(w[4 + o],  cm, s);
            s = fmaf(w[8 + o],  rm, s);
            s = fmaf(w[12 + o], lc, s);   // ky=1
            s = fmaf(w[16 + o], cc, s);
            s = fmaf(w[20 + o], rc, s);
            s = fmaf(w[24 + o], lp, s);   // ky=2
            s = fmaf(w[28 + o], cp, s);
            s = fmaf(w[32 + o], rp, s);
            acc[o] = s;
        }
    }

    // epilogue: 4 oc per thread at its pixel
    float ss = 0.f;
    {
        int oc0 = och * 16 + ocg * 4;
        int gbase = img * 8192 + oc0 * 256 + y * 16 + x;
        const float* bias = phib + K * 32 + oc0;
#pragma unroll
        for (int oi = 0; oi < 4; ++oi) {
            float conv = acc[oi] + bias[oi];
            float hval = 0.5f * S_hu[(oc0 + oi) * 128 + ry * 16 + x] + 0.5f * conv;
            float fh = fhat[gbase + oi * 256] + hval;
            fhat[gbase + oi * 256] = fh;
            if (LAST) dout[gbase + oi * 256] = fh;
            float d = fh - fin[gbase + oi * 256];
            ss = fmaf(d, d, ss);
        }
    }
    int lane = tid & 63;
#pragma unroll
    for (int m = 1; m < 64; m <<= 1) ss += __shfl_xor(ss, m, 64);
    if (lane == 0) red[tid >> 6] = ss;
    __syncthreads();
    if (tid == 0) atomicAdd(lossAcc, red[0] + red[1] + red[2] + red[3]);
}

__global__ void __launch_bounds__(256) k_final(const float* __restrict__ lossAcc,
                                               const int* __restrict__ hist,
                                               float* __restrict__ out) {
    __shared__ float red[256];
    int tid = threadIdx.x;
    float s = 0.f;
    for (int i = tid; i < 4096; i += 256) {
        float p = (float)hist[i] * (1.f / 32768.f);
        s += p * logf(p + 1e-10f);
    }
    red[tid] = s;
    __syncthreads();
    for (int k = 128; k > 0; k >>= 1) {
        if (tid < k) red[tid] += red[tid + k];
        __syncthreads();
    }
    if (tid == 0) {
        out[1048577] = expf(-red[0]);
        float L = 0.f;
        for (int si = 0; si < 10; ++si) L += lossAcc[si];
        out[1048576] = L * 1.25f / 1048576.f * 0.1f;
    }
}

// ------------------------------ launch -------------------------------------

extern "C" void kernel_launch(void* const* d_in, const int* in_sizes, int n_in,
                              void* d_out, int out_size, void* d_ws, size_t ws_size,
                              hipStream_t stream) {
    const float* f_in  = (const float*)d_in[0];   // [128,32,16,16]
    const float* cbook = (const float*)d_in[1];   // [4096,32]
    const float* phiw  = (const float*)d_in[2];   // [4,32,32,3,3]
    const float* phib  = (const float*)d_in[3];   // [4,32]
    float* out = (float*)d_out;
    char* base = (char*)d_ws;

    float* fhat    = (float*)(base);                       // 4,194,304 B
    float* lossAcc = (float*)(base + 4194304);             // 64 B
    int*   hist    = (int*)  (base + 4194368);             // 16,384 B
    float* wT      = (float*)(base + 4210752);             // 147,456 B
    float* um      = (float*)(base + 4358208);             // 9,216 B
    _Float16* cbh  = (_Float16*)(base + 4367424);          // 262,144 B
    _Float16* cbl  = (_Float16*)(base + 4629568);          // 262,144 B
    _Float16* xh   = (_Float16*)(base + 4891712);          // 2,097,152 B
    _Float16* xl   = (_Float16*)(base + 6988864);          // 2,097,152 B
    unsigned* bestp = (unsigned*)(base + 9086016);         // 4,194,304 B (32 segs)

    k_setup<<<1185, 256, 0, stream>>>(cbook, phiw, cbh, cbl, wT, um, fhat, lossAcc);

#define SCALE(SI, PN, K, LAST)                                                         \
    {                                                                                  \
        constexpr int T = 128 * PN * PN;                                               \
        constexpr int Tp = ((T + 511) / 512) * 512;                                    \
        constexpr int TB = Tp / 512;                                                   \
        k_down<PN><<<(Tp * 32) / 256, 256, 0, stream>>>(f_in, fhat, xh, xl);           \
        k_quant<PN, 32><<<TB * 32, 256, 0, stream>>>(                                  \
            (const half8*)xh, (const half8*)xl, (const half8*)cbh,                     \
            (const half8*)cbl, bestp);                                                 \
        k_upconv<PN, 32, K, LAST><<<1024, 256, 0, stream>>>(                           \
            f_in, fhat, cbook, bestp, wT, phib, um + SI * 256, lossAcc + SI, hist,     \
            out);                                                                      \
    }
    SCALE(0, 1, 0, false);
    SCALE(1, 2, 0, false);
    SCALE(2, 3, 0, false);
    SCALE(3, 4, 1, false);
    SCALE(4, 5, 1, false);
    SCALE(5, 6, 2, false);
    SCALE(6, 8, 2, false);
    SCALE(7, 10, 2, false);
    SCALE(8, 13, 3, false);
    SCALE(9, 16, 3, true);
#undef SCALE
    k_final<<<1, 256, 0, stream>>>(lossAcc, hist, out);
}